// Round 1
// baseline (789.595 us; speedup 1.0000x reference)
//
#include <hip/hip_runtime.h>
#include <hip/hip_bf16.h>

#define TD 128   // feature dim, fixed by problem

// ---------------- degree histogram ----------------
__global__ __launch_bounds__(256) void k_deg(const int* __restrict__ ei, int* __restrict__ deg, int E_) {
    int e = blockIdx.x * 256 + threadIdx.x;
    if (e < E_) atomicAdd(&deg[ei[E_ + e]], 1);   // dst = row 1 of edge_index
}

__global__ __launch_bounds__(256) void k_dinv(const int* __restrict__ deg, float* __restrict__ dinv, int n) {
    int i = blockIdx.x * 256 + threadIdx.x;
    if (i < n) {
        int d = deg[i];
        dinv[i] = (d > 0) ? 1.0f / sqrtf((float)d) : 0.0f;
    }
}

// ---------------- exclusive scan (3-kernel hierarchical) ----------------
__global__ __launch_bounds__(256) void k_scan1(const int* __restrict__ deg, int* __restrict__ rowptr,
                                               int* __restrict__ bsums, int n) {
    __shared__ int wsum[4];
    int t = threadIdx.x;
    int base = blockIdx.x * 1024 + t * 4;
    int a0 = 0, a1 = 0, a2 = 0, a3 = 0;
    if (base + 3 < n) {
        int4 v = *(const int4*)(deg + base);
        a0 = v.x; a1 = v.y; a2 = v.z; a3 = v.w;
    } else {
        if (base     < n) a0 = deg[base];
        if (base + 1 < n) a1 = deg[base + 1];
        if (base + 2 < n) a2 = deg[base + 2];
        if (base + 3 < n) a3 = deg[base + 3];
    }
    int s1 = a0 + a1, s2 = s1 + a2, tot = s2 + a3;
    int lane = t & 63, wv = t >> 6;
    int x = tot;
#pragma unroll
    for (int off = 1; off < 64; off <<= 1) {
        int y = __shfl_up(x, off);
        if (lane >= off) x += y;
    }
    if (lane == 63) wsum[wv] = x;
    __syncthreads();
    int woff = 0;
    for (int w = 0; w < wv; ++w) woff += wsum[w];
    int excl = woff + x - tot;
    if (base     < n) rowptr[base]     = excl;
    if (base + 1 < n) rowptr[base + 1] = excl + a0;
    if (base + 2 < n) rowptr[base + 2] = excl + s1;
    if (base + 3 < n) rowptr[base + 3] = excl + s2;
    if (t == 255) bsums[blockIdx.x] = woff + x;   // block total
}

__global__ void k_scan2(int* __restrict__ bsums, int nb, int* __restrict__ rowptrN) {
    if (threadIdx.x == 0 && blockIdx.x == 0) {
        int run = 0;
        for (int i = 0; i < nb; ++i) { int v = bsums[i]; bsums[i] = run; run += v; }
        *rowptrN = run;   // rowptr[N] = E
    }
}

__global__ __launch_bounds__(256) void k_scan3(int* __restrict__ rowptr, const int* __restrict__ bsums, int n) {
    int i = blockIdx.x * 256 + threadIdx.x;
    if (i < n) rowptr[i] += bsums[i >> 10];
}

// ---------------- CSR bucket scatter ----------------
__global__ __launch_bounds__(256) void k_scatter(const int* __restrict__ ei, int* __restrict__ cursor,
                                                 int* __restrict__ esrc, int E_) {
    int e = blockIdx.x * 256 + threadIdx.x;
    if (e < E_) {
        int s = ei[e];
        int d = ei[E_ + e];
        int p = atomicAdd(&cursor[d], 1);
        esrc[p] = s;
    }
}

// ---------------- f32 GEMM: out[r][c] = scale[r] * sum_k X[r][k]*W[k][c] ----------------
// 256 thr/block, 32 rows/block, 16 outputs/thread (2 rows x 8 cols).
__global__ __launch_bounds__(256) void k_gemm(const float* __restrict__ X, const float* __restrict__ W,
                                              const float* __restrict__ scale, float* __restrict__ out,
                                              int nrows) {
    __shared__ __align__(16) float Wl[TD * TD];      // 64 KB
    __shared__ __align__(16) float Xl[32 * 132];     // padded stride (bank-conflict-free x reads)
    const int t = threadIdx.x;
    {   // W -> LDS, 4096 float4
        const float4* W4 = (const float4*)W;
        float4* Wl4 = (float4*)Wl;
#pragma unroll
        for (int i = 0; i < 16; ++i) Wl4[t + i * 256] = W4[t + i * 256];
    }
    const int rbase = blockIdx.x * 32;
    for (int i = t; i < 1024; i += 256) {            // X tile -> LDS
        int row = i >> 5, c4 = i & 31;
        int gr = rbase + row;
        float4 v = make_float4(0.f, 0.f, 0.f, 0.f);
        if (gr < nrows) v = ((const float4*)(X + (size_t)gr * TD))[c4];
        ((float4*)(Xl + row * 132))[c4] = v;
    }
    __syncthreads();

    const int tx = t & 15;    // col group: cols tx*4..+3 and 64+tx*4..+3
    const int ty = t >> 4;    // rows ty*2, ty*2+1
    const int r0 = ty * 2;
    const int c0 = tx * 4;
    float a00=0,a01=0,a02=0,a03=0,a04=0,a05=0,a06=0,a07=0;
    float a10=0,a11=0,a12=0,a13=0,a14=0,a15=0,a16=0,a17=0;
#pragma unroll 8
    for (int k = 0; k < TD; ++k) {
        float xa = Xl[r0 * 132 + k];
        float xb = Xl[r0 * 132 + 132 + k];
        float4 w0 = *(const float4*)&Wl[k * TD + c0];
        float4 w1 = *(const float4*)&Wl[k * TD + 64 + c0];
        a00 = fmaf(xa, w0.x, a00); a01 = fmaf(xa, w0.y, a01);
        a02 = fmaf(xa, w0.z, a02); a03 = fmaf(xa, w0.w, a03);
        a04 = fmaf(xa, w1.x, a04); a05 = fmaf(xa, w1.y, a05);
        a06 = fmaf(xa, w1.z, a06); a07 = fmaf(xa, w1.w, a07);
        a10 = fmaf(xb, w0.x, a10); a11 = fmaf(xb, w0.y, a11);
        a12 = fmaf(xb, w0.z, a12); a13 = fmaf(xb, w0.w, a13);
        a14 = fmaf(xb, w1.x, a14); a15 = fmaf(xb, w1.y, a15);
        a16 = fmaf(xb, w1.z, a16); a17 = fmaf(xb, w1.w, a17);
    }
    int gr0 = rbase + r0;
    if (gr0 < nrows) {
        float s0 = scale[gr0];
        float4* o = (float4*)(out + (size_t)gr0 * TD);
        o[tx]      = make_float4(a00 * s0, a01 * s0, a02 * s0, a03 * s0);
        o[16 + tx] = make_float4(a04 * s0, a05 * s0, a06 * s0, a07 * s0);
    }
    if (gr0 + 1 < nrows) {
        float s1 = scale[gr0 + 1];
        float4* o = (float4*)(out + (size_t)(gr0 + 1) * TD);
        o[tx]      = make_float4(a10 * s1, a11 * s1, a12 * s1, a13 * s1);
        o[16 + tx] = make_float4(a14 * s1, a15 * s1, a16 * s1, a17 * s1);
    }
}

// ---------------- CSR aggregation: out[n] = maybe_relu(dinv[n]*sum_{e in(n)} hs[src_e] + b) ----------------
// one node per half-wave, float4 lanes (32 lanes x 16 B = 512 B coalesced row loads)
__global__ __launch_bounds__(256) void k_agg(const float* __restrict__ hs, const int* __restrict__ rowptr,
                                             const int* __restrict__ esrc, const float* __restrict__ dinv,
                                             const float* __restrict__ bias, float* __restrict__ out,
                                             int n, int relu) {
    int node = blockIdx.x * 8 + (threadIdx.x >> 5);
    int c4 = threadIdx.x & 31;
    if (node >= n) return;
    int s = rowptr[node], e = rowptr[node + 1];
    const float4* h4 = (const float4*)hs;
    float ax = 0.f, ay = 0.f, az = 0.f, aw = 0.f;
    for (int i = s; i < e; ++i) {
        int src = esrc[i];                       // broadcast within half-wave
        float4 v = h4[(size_t)src * 32 + c4];
        ax += v.x; ay += v.y; az += v.z; aw += v.w;
    }
    float di = dinv[node];
    float4 b = ((const float4*)bias)[c4];
    float vx = fmaf(di, ax, b.x);
    float vy = fmaf(di, ay, b.y);
    float vz = fmaf(di, az, b.z);
    float vw = fmaf(di, aw, b.w);
    if (relu) {
        vx = fmaxf(vx, 0.f); vy = fmaxf(vy, 0.f);
        vz = fmaxf(vz, 0.f); vw = fmaxf(vw, 0.f);
    }
    ((float4*)out)[(size_t)node * 32 + c4] = make_float4(vx, vy, vz, vw);
}

// ---------------- scoring: out[e] = z[head]^T W[rel] z[tail] ----------------
// one block (128 thr) per triple; thread j owns column j:
//   acc_j = sum_i zh[i]*W[i][j]  (coalesced W row loads), then *zt[j], block-reduce.
__global__ __launch_bounds__(128) void k_score(const float* __restrict__ z, const float* __restrict__ relW,
                                               const int* __restrict__ rel, const int* __restrict__ head,
                                               const int* __restrict__ tail, float* __restrict__ out, int es) {
    int e = blockIdx.x;
    int j = threadIdx.x;
    __shared__ float zh[TD];
    __shared__ float red[2];
    int r = rel[e], h = head[e], tl = tail[e];
    zh[j] = z[(size_t)h * TD + j];
    float ztj = z[(size_t)tl * TD + j];
    __syncthreads();
    const float* W = relW + (size_t)r * TD * TD;
    float acc = 0.f;
#pragma unroll 8
    for (int i = 0; i < TD; ++i) acc = fmaf(zh[i], W[i * TD + j], acc);
    acc *= ztj;
#pragma unroll
    for (int off = 32; off > 0; off >>= 1) acc += __shfl_down(acc, off);
    if ((j & 63) == 0) red[j >> 6] = acc;
    __syncthreads();
    if (j == 0) out[e] = red[0] + red[1];
}

extern "C" void kernel_launch(void* const* d_in, const int* in_sizes, int n_in,
                              void* d_out, int out_size, void* d_ws, size_t ws_size,
                              hipStream_t stream) {
    const float* x0   = (const float*)d_in[0];
    const float* W1   = (const float*)d_in[1];
    const float* b1   = (const float*)d_in[2];
    const float* W2   = (const float*)d_in[3];
    const float* b2   = (const float*)d_in[4];
    const float* relW = (const float*)d_in[5];
    const int*   ei   = (const int*)d_in[6];
    const int*   rel  = (const int*)d_in[7];
    const int*   head = (const int*)d_in[8];
    const int*   tail = (const int*)d_in[9];
    float* outp = (float*)d_out;

    const int N_  = in_sizes[0] / TD;
    const int E_  = in_sizes[6] / 2;
    const int ES_ = in_sizes[7];
    const int nb  = (N_ + 1023) / 1024;

    char* p = (char*)d_ws;
    auto alloc = [&](size_t bytes) { char* r = p; p += (bytes + 255) & ~(size_t)255; return r; };
    int*   deg    = (int*)  alloc((size_t)N_ * 4);
    float* dinv   = (float*)alloc((size_t)N_ * 4);
    int*   rowptr = (int*)  alloc(((size_t)N_ + 1) * 4);
    int*   bsums  = (int*)  alloc((size_t)nb * 4);
    int*   cursor = (int*)  alloc((size_t)N_ * 4);
    int*   esrc   = (int*)  alloc((size_t)E_ * 4);
    float* bufA   = (float*)alloc((size_t)N_ * TD * 4);  // h-scaled
    float* bufB   = (float*)alloc((size_t)N_ * TD * 4);  // conv out

    hipMemsetAsync(deg, 0, (size_t)N_ * 4, stream);
    k_deg    <<<(E_ + 255) / 256, 256, 0, stream>>>(ei, deg, E_);
    k_dinv   <<<(N_ + 255) / 256, 256, 0, stream>>>(deg, dinv, N_);
    k_scan1  <<<nb, 256, 0, stream>>>(deg, rowptr, bsums, N_);
    k_scan2  <<<1, 64, 0, stream>>>(bsums, nb, rowptr + N_);
    k_scan3  <<<(N_ + 255) / 256, 256, 0, stream>>>(rowptr, bsums, N_);
    hipMemcpyAsync(cursor, rowptr, (size_t)N_ * 4, hipMemcpyDeviceToDevice, stream);
    k_scatter<<<(E_ + 255) / 256, 256, 0, stream>>>(ei, cursor, esrc, E_);

    // conv1: bufA = dinv * (x0 @ W1); bufB = relu(dinv*agg(bufA) + b1)
    k_gemm<<<(N_ + 31) / 32, 256, 0, stream>>>(x0, W1, dinv, bufA, N_);
    k_agg <<<(N_ + 7) / 8, 256, 0, stream>>>(bufA, rowptr, esrc, dinv, b1, bufB, N_, 1);
    // conv2: bufA = dinv * (bufB @ W2); bufB = dinv*agg(bufA) + b2  (= z)
    k_gemm<<<(N_ + 31) / 32, 256, 0, stream>>>(bufB, W2, dinv, bufA, N_);
    k_agg <<<(N_ + 7) / 8, 256, 0, stream>>>(bufA, rowptr, esrc, dinv, b2, bufB, N_, 0);

    k_score<<<ES_, 128, 0, stream>>>(bufB, relW, rel, head, tail, outp, ES_);
}

// Round 3
// 678.342 us; speedup vs baseline: 1.1640x; 1.1640x over previous
//
#include <hip/hip_runtime.h>
#include <hip/hip_bf16.h>

#define TD 128   // feature dim, fixed by problem

// ---------------- pass 1: degree + within-bucket rank (single atomic pass) ----------------
__global__ __launch_bounds__(256) void k_rank(const int* __restrict__ ei, int* __restrict__ deg,
                                              int* __restrict__ rank, int E_) {
    int e = blockIdx.x * 256 + threadIdx.x;
    if (e < E_) rank[e] = atomicAdd(&deg[ei[E_ + e]], 1);   // dst = row 1
}

__global__ __launch_bounds__(256) void k_dinv(const int* __restrict__ deg, float* __restrict__ dinv, int n) {
    int i = blockIdx.x * 256 + threadIdx.x;
    if (i < n) {
        int d = deg[i];
        dinv[i] = (d > 0) ? 1.0f / sqrtf((float)d) : 0.0f;
    }
}

// ---------------- exclusive scan (3-kernel hierarchical) ----------------
__global__ __launch_bounds__(256) void k_scan1(const int* __restrict__ deg, int* __restrict__ rowptr,
                                               int* __restrict__ bsums, int n) {
    __shared__ int wsum[4];
    int t = threadIdx.x;
    int base = blockIdx.x * 1024 + t * 4;
    int a0 = 0, a1 = 0, a2 = 0, a3 = 0;
    if (base + 3 < n) {
        int4 v = *(const int4*)(deg + base);
        a0 = v.x; a1 = v.y; a2 = v.z; a3 = v.w;
    } else {
        if (base     < n) a0 = deg[base];
        if (base + 1 < n) a1 = deg[base + 1];
        if (base + 2 < n) a2 = deg[base + 2];
        if (base + 3 < n) a3 = deg[base + 3];
    }
    int s1 = a0 + a1, s2 = s1 + a2, tot = s2 + a3;
    int lane = t & 63, wv = t >> 6;
    int x = tot;
#pragma unroll
    for (int off = 1; off < 64; off <<= 1) {
        int y = __shfl_up(x, off);
        if (lane >= off) x += y;
    }
    if (lane == 63) wsum[wv] = x;
    __syncthreads();
    int woff = 0;
    for (int w = 0; w < wv; ++w) woff += wsum[w];
    int excl = woff + x - tot;
    if (base     < n) rowptr[base]     = excl;
    if (base + 1 < n) rowptr[base + 1] = excl + a0;
    if (base + 2 < n) rowptr[base + 2] = excl + s1;
    if (base + 3 < n) rowptr[base + 3] = excl + s2;
    if (t == 255) bsums[blockIdx.x] = woff + x;   // block total
}

// parallel single-block scan of block sums (nb <= 1024)
__global__ __launch_bounds__(256) void k_scan2(int* __restrict__ bsums, int nb, int* __restrict__ rowptrN) {
    __shared__ int wsum[4];
    int t = threadIdx.x;
    int base = t * 4;
    int a0 = (base     < nb) ? bsums[base]     : 0;
    int a1 = (base + 1 < nb) ? bsums[base + 1] : 0;
    int a2 = (base + 2 < nb) ? bsums[base + 2] : 0;
    int a3 = (base + 3 < nb) ? bsums[base + 3] : 0;
    int s1 = a0 + a1, s2 = s1 + a2, tot = s2 + a3;
    int lane = t & 63, wv = t >> 6;
    int x = tot;
#pragma unroll
    for (int off = 1; off < 64; off <<= 1) {
        int y = __shfl_up(x, off);
        if (lane >= off) x += y;
    }
    if (lane == 63) wsum[wv] = x;
    __syncthreads();
    int woff = 0;
    for (int w = 0; w < wv; ++w) woff += wsum[w];
    int excl = woff + x - tot;
    if (base     < nb) bsums[base]     = excl;
    if (base + 1 < nb) bsums[base + 1] = excl + a0;
    if (base + 2 < nb) bsums[base + 2] = excl + s1;
    if (base + 3 < nb) bsums[base + 3] = excl + s2;
    if (t == 255) *rowptrN = woff + x;   // grand total = E
}

__global__ __launch_bounds__(256) void k_scan3(int* __restrict__ rowptr, const int* __restrict__ bsums, int n) {
    int i = blockIdx.x * 256 + threadIdx.x;
    if (i < n) rowptr[i] += bsums[i >> 10];
}

// ---------------- pass 2: atomic-free placement ----------------
__global__ __launch_bounds__(256) void k_place(const int* __restrict__ ei, const int* __restrict__ rowptr,
                                               const int* __restrict__ rank, int* __restrict__ esrc, int E_) {
    int e = blockIdx.x * 256 + threadIdx.x;
    if (e < E_) {
        int s = ei[e];
        int d = ei[E_ + e];
        esrc[rowptr[d] + rank[e]] = s;
    }
}

// ---------------- f32 GEMM: out[r][c] = scale[r] * sum_k X[r][k]*W[k][c] ----------------
__global__ __launch_bounds__(256) void k_gemm(const float* __restrict__ X, const float* __restrict__ W,
                                              const float* __restrict__ scale, float* __restrict__ out,
                                              int nrows) {
    __shared__ __align__(16) float Wl[TD * TD];      // 64 KB
    __shared__ __align__(16) float Xl[32 * 132];
    const int t = threadIdx.x;
    {
        const float4* W4 = (const float4*)W;
        float4* Wl4 = (float4*)Wl;
#pragma unroll
        for (int i = 0; i < 16; ++i) Wl4[t + i * 256] = W4[t + i * 256];
    }
    const int rbase = blockIdx.x * 32;
    for (int i = t; i < 1024; i += 256) {
        int row = i >> 5, c4 = i & 31;
        int gr = rbase + row;
        float4 v = make_float4(0.f, 0.f, 0.f, 0.f);
        if (gr < nrows) v = ((const float4*)(X + (size_t)gr * TD))[c4];
        ((float4*)(Xl + row * 132))[c4] = v;
    }
    __syncthreads();

    const int tx = t & 15;
    const int ty = t >> 4;
    const int r0 = ty * 2;
    const int c0 = tx * 4;
    float a00=0,a01=0,a02=0,a03=0,a04=0,a05=0,a06=0,a07=0;
    float a10=0,a11=0,a12=0,a13=0,a14=0,a15=0,a16=0,a17=0;
#pragma unroll 8
    for (int k = 0; k < TD; ++k) {
        float xa = Xl[r0 * 132 + k];
        float xb = Xl[r0 * 132 + 132 + k];
        float4 w0 = *(const float4*)&Wl[k * TD + c0];
        float4 w1 = *(const float4*)&Wl[k * TD + 64 + c0];
        a00 = fmaf(xa, w0.x, a00); a01 = fmaf(xa, w0.y, a01);
        a02 = fmaf(xa, w0.z, a02); a03 = fmaf(xa, w0.w, a03);
        a04 = fmaf(xa, w1.x, a04); a05 = fmaf(xa, w1.y, a05);
        a06 = fmaf(xa, w1.z, a06); a07 = fmaf(xa, w1.w, a07);
        a10 = fmaf(xb, w0.x, a10); a11 = fmaf(xb, w0.y, a11);
        a12 = fmaf(xb, w0.z, a12); a13 = fmaf(xb, w0.w, a13);
        a14 = fmaf(xb, w1.x, a14); a15 = fmaf(xb, w1.y, a15);
        a16 = fmaf(xb, w1.z, a16); a17 = fmaf(xb, w1.w, a17);
    }
    int gr0 = rbase + r0;
    if (gr0 < nrows) {
        float s0 = scale[gr0];
        float4* o = (float4*)(out + (size_t)gr0 * TD);
        o[tx]      = make_float4(a00 * s0, a01 * s0, a02 * s0, a03 * s0);
        o[16 + tx] = make_float4(a04 * s0, a05 * s0, a06 * s0, a07 * s0);
    }
    if (gr0 + 1 < nrows) {
        float s1 = scale[gr0 + 1];
        float4* o = (float4*)(out + (size_t)(gr0 + 1) * TD);
        o[tx]      = make_float4(a10 * s1, a11 * s1, a12 * s1, a13 * s1);
        o[16 + tx] = make_float4(a14 * s1, a15 * s1, a16 * s1, a17 * s1);
    }
}

// ---------------- CSR aggregation, DOUBLE accumulation (order-invariant) ----------------
// one node per half-wave, float4 lanes; f64 accumulators make the sum independent of
// the (nondeterministic) esrc permutation from k_rank's atomics.
__global__ __launch_bounds__(256) void k_agg(const float* __restrict__ hs, const int* __restrict__ rowptr,
                                             const int* __restrict__ esrc, const float* __restrict__ dinv,
                                             const float* __restrict__ bias, float* __restrict__ out,
                                             int n, int relu) {
    int node = blockIdx.x * 8 + (threadIdx.x >> 5);
    int c4 = threadIdx.x & 31;
    if (node >= n) return;
    int s = rowptr[node], e = rowptr[node + 1];
    const float4* h4 = (const float4*)hs;
    double ax = 0.0, ay = 0.0, az = 0.0, aw = 0.0;
    double bx = 0.0, by = 0.0, bz = 0.0, bw = 0.0;
    int i = s;
    for (; i + 2 <= e; i += 2) {
        int s0 = esrc[i];
        int s1 = esrc[i + 1];
        float4 v0 = h4[(size_t)s0 * 32 + c4];
        float4 v1 = h4[(size_t)s1 * 32 + c4];
        ax += (double)v0.x; ay += (double)v0.y; az += (double)v0.z; aw += (double)v0.w;
        bx += (double)v1.x; by += (double)v1.y; bz += (double)v1.z; bw += (double)v1.w;
    }
    if (i < e) {
        float4 v = h4[(size_t)esrc[i] * 32 + c4];
        ax += (double)v.x; ay += (double)v.y; az += (double)v.z; aw += (double)v.w;
    }
    ax += bx; ay += by; az += bz; aw += bw;
    double di = (double)dinv[node];
    float4 b = ((const float4*)bias)[c4];
    float vx = (float)(di * ax + (double)b.x);
    float vy = (float)(di * ay + (double)b.y);
    float vz = (float)(di * az + (double)b.z);
    float vw = (float)(di * aw + (double)b.w);
    if (relu) {
        vx = fmaxf(vx, 0.f); vy = fmaxf(vy, 0.f);
        vz = fmaxf(vz, 0.f); vw = fmaxf(vw, 0.f);
    }
    ((float4*)out)[(size_t)node * 32 + c4] = make_float4(vx, vy, vz, vw);
}

// ---------------- scoring: out[e] = z[head]^T W[rel] z[tail]  (R1-proven version) ----------------
__global__ __launch_bounds__(128) void k_score(const float* __restrict__ z, const float* __restrict__ relW,
                                               const int* __restrict__ rel, const int* __restrict__ head,
                                               const int* __restrict__ tail, float* __restrict__ out, int es) {
    int e = blockIdx.x;
    int j = threadIdx.x;
    __shared__ float zh[TD];
    __shared__ float red[2];
    int r = rel[e], h = head[e], tl = tail[e];
    zh[j] = z[(size_t)h * TD + j];
    float ztj = z[(size_t)tl * TD + j];
    __syncthreads();
    const float* W = relW + (size_t)r * TD * TD;
    float acc = 0.f;
#pragma unroll 8
    for (int i = 0; i < TD; ++i) acc = fmaf(zh[i], W[i * TD + j], acc);
    acc *= ztj;
#pragma unroll
    for (int off = 32; off > 0; off >>= 1) acc += __shfl_down(acc, off);
    if ((j & 63) == 0) red[j >> 6] = acc;
    __syncthreads();
    if (j == 0) out[e] = red[0] + red[1];
}

extern "C" void kernel_launch(void* const* d_in, const int* in_sizes, int n_in,
                              void* d_out, int out_size, void* d_ws, size_t ws_size,
                              hipStream_t stream) {
    const float* x0   = (const float*)d_in[0];
    const float* W1   = (const float*)d_in[1];
    const float* b1   = (const float*)d_in[2];
    const float* W2   = (const float*)d_in[3];
    const float* b2   = (const float*)d_in[4];
    const float* relW = (const float*)d_in[5];
    const int*   ei   = (const int*)d_in[6];
    const int*   rel  = (const int*)d_in[7];
    const int*   head = (const int*)d_in[8];
    const int*   tail = (const int*)d_in[9];
    float* outp = (float*)d_out;

    const int N_  = in_sizes[0] / TD;
    const int E_  = in_sizes[6] / 2;
    const int ES_ = in_sizes[7];
    const int nb  = (N_ + 1023) / 1024;

    // layout kept byte-compatible with the R1 (fully passing) footprint
    char* p = (char*)d_ws;
    auto alloc = [&](size_t bytes) { char* r = p; p += (bytes + 255) & ~(size_t)255; return r; };
    int*   deg    = (int*)  alloc((size_t)N_ * 4);
    float* dinv   = (float*)alloc((size_t)N_ * 4);
    int*   rowptr = (int*)  alloc(((size_t)N_ + 1) * 4);
    int*   bsums  = (int*)  alloc((size_t)nb * 4);
    int*   unused = (int*)  alloc((size_t)N_ * 4);  (void)unused;  // R1 'cursor' slot
    int*   esrc   = (int*)  alloc((size_t)E_ * 4);
    float* bufA   = (float*)alloc((size_t)N_ * TD * 4);
    float* bufB   = (float*)alloc((size_t)N_ * TD * 4);
    int*   rank   = (int*)bufA;   // alias: dead before first k_gemm writes bufA

    hipMemsetAsync(deg, 0, (size_t)N_ * 4, stream);
    k_rank  <<<(E_ + 255) / 256, 256, 0, stream>>>(ei, deg, rank, E_);
    k_dinv  <<<(N_ + 255) / 256, 256, 0, stream>>>(deg, dinv, N_);
    k_scan1 <<<nb, 256, 0, stream>>>(deg, rowptr, bsums, N_);
    k_scan2 <<<1, 256, 0, stream>>>(bsums, nb, rowptr + N_);
    k_scan3 <<<(N_ + 255) / 256, 256, 0, stream>>>(rowptr, bsums, N_);
    k_place <<<(E_ + 255) / 256, 256, 0, stream>>>(ei, rowptr, rank, esrc, E_);

    // conv1: bufA = dinv * (x0 @ W1); bufB = relu(dinv*agg(bufA) + b1)
    k_gemm<<<(N_ + 31) / 32, 256, 0, stream>>>(x0, W1, dinv, bufA, N_);
    k_agg <<<(N_ + 7) / 8, 256, 0, stream>>>(bufA, rowptr, esrc, dinv, b1, bufB, N_, 1);
    // conv2
    k_gemm<<<(N_ + 31) / 32, 256, 0, stream>>>(bufB, W2, dinv, bufA, N_);
    k_agg <<<(N_ + 7) / 8, 256, 0, stream>>>(bufA, rowptr, esrc, dinv, b2, bufB, N_, 0);

    k_score<<<ES_, 128, 0, stream>>>(bufB, relW, rel, head, tail, outp, ES_);
}

// Round 4
// 562.993 us; speedup vs baseline: 1.4025x; 1.2049x over previous
//
#include <hip/hip_runtime.h>
#include <hip/hip_bf16.h>

#define TD 128   // feature dim, fixed by problem

static __device__ __forceinline__ unsigned short f2bf(float f) {
    unsigned int u = __float_as_uint(f);
    u += 0x7fffu + ((u >> 16) & 1u);   // round-to-nearest-even
    return (unsigned short)(u >> 16);
}

// ---------------- pass 1: degree + within-bucket rank (single atomic pass) ----------------
__global__ __launch_bounds__(256) void k_rank(const int* __restrict__ ei, int* __restrict__ deg,
                                              int* __restrict__ rank, int E_) {
    int e = blockIdx.x * 256 + threadIdx.x;
    if (e < E_) rank[e] = atomicAdd(&deg[ei[E_ + e]], 1);   // dst = row 1
}

__global__ __launch_bounds__(256) void k_dinv(const int* __restrict__ deg, float* __restrict__ dinv, int n) {
    int i = blockIdx.x * 256 + threadIdx.x;
    if (i < n) {
        int d = deg[i];
        dinv[i] = (d > 0) ? 1.0f / sqrtf((float)d) : 0.0f;
    }
}

// ---------------- exclusive scan (3-kernel hierarchical) ----------------
__global__ __launch_bounds__(256) void k_scan1(const int* __restrict__ deg, int* __restrict__ rowptr,
                                               int* __restrict__ bsums, int n) {
    __shared__ int wsum[4];
    int t = threadIdx.x;
    int base = blockIdx.x * 1024 + t * 4;
    int a0 = 0, a1 = 0, a2 = 0, a3 = 0;
    if (base + 3 < n) {
        int4 v = *(const int4*)(deg + base);
        a0 = v.x; a1 = v.y; a2 = v.z; a3 = v.w;
    } else {
        if (base     < n) a0 = deg[base];
        if (base + 1 < n) a1 = deg[base + 1];
        if (base + 2 < n) a2 = deg[base + 2];
        if (base + 3 < n) a3 = deg[base + 3];
    }
    int s1 = a0 + a1, s2 = s1 + a2, tot = s2 + a3;
    int lane = t & 63, wv = t >> 6;
    int x = tot;
#pragma unroll
    for (int off = 1; off < 64; off <<= 1) {
        int y = __shfl_up(x, off);
        if (lane >= off) x += y;
    }
    if (lane == 63) wsum[wv] = x;
    __syncthreads();
    int woff = 0;
    for (int w = 0; w < wv; ++w) woff += wsum[w];
    int excl = woff + x - tot;
    if (base     < n) rowptr[base]     = excl;
    if (base + 1 < n) rowptr[base + 1] = excl + a0;
    if (base + 2 < n) rowptr[base + 2] = excl + s1;
    if (base + 3 < n) rowptr[base + 3] = excl + s2;
    if (t == 255) bsums[blockIdx.x] = woff + x;   // block total
}

// parallel single-block scan of block sums (nb <= 1024)
__global__ __launch_bounds__(256) void k_scan2(int* __restrict__ bsums, int nb, int* __restrict__ rowptrN) {
    __shared__ int wsum[4];
    int t = threadIdx.x;
    int base = t * 4;
    int a0 = (base     < nb) ? bsums[base]     : 0;
    int a1 = (base + 1 < nb) ? bsums[base + 1] : 0;
    int a2 = (base + 2 < nb) ? bsums[base + 2] : 0;
    int a3 = (base + 3 < nb) ? bsums[base + 3] : 0;
    int s1 = a0 + a1, s2 = s1 + a2, tot = s2 + a3;
    int lane = t & 63, wv = t >> 6;
    int x = tot;
#pragma unroll
    for (int off = 1; off < 64; off <<= 1) {
        int y = __shfl_up(x, off);
        if (lane >= off) x += y;
    }
    if (lane == 63) wsum[wv] = x;
    __syncthreads();
    int woff = 0;
    for (int w = 0; w < wv; ++w) woff += wsum[w];
    int excl = woff + x - tot;
    if (base     < nb) bsums[base]     = excl;
    if (base + 1 < nb) bsums[base + 1] = excl + a0;
    if (base + 2 < nb) bsums[base + 2] = excl + s1;
    if (base + 3 < nb) bsums[base + 3] = excl + s2;
    if (t == 255) *rowptrN = woff + x;   // grand total = E
}

__global__ __launch_bounds__(256) void k_scan3(int* __restrict__ rowptr, const int* __restrict__ bsums, int n) {
    int i = blockIdx.x * 256 + threadIdx.x;
    if (i < n) rowptr[i] += bsums[i >> 10];
}

// ---------------- pass 2: atomic-free placement ----------------
__global__ __launch_bounds__(256) void k_place(const int* __restrict__ ei, const int* __restrict__ rowptr,
                                               const int* __restrict__ rank, int* __restrict__ esrc, int E_) {
    int e = blockIdx.x * 256 + threadIdx.x;
    if (e < E_) {
        int s = ei[e];
        int d = ei[E_ + e];
        esrc[rowptr[d] + rank[e]] = s;
    }
}

// ---------------- f32 GEMM -> bf16 out: out[r][c] = bf16(scale[r] * sum_k X[r][k]*W[k][c]) ----------------
// 256 thr, 128-row tiles (persistent grid-stride), 8 rows x 8 cols per thread.
// LDS-throughput balanced: 4 b128 LDS reads per k per wave vs 128 VALU-cyc of FMA.
// Thread rows interleaved (ty + 16j) so the 4 per-wave X addresses land on distinct bank groups.
__global__ __launch_bounds__(256) void k_gemm(const float* __restrict__ X, const float* __restrict__ W,
                                              const float* __restrict__ scale, unsigned short* __restrict__ out,
                                              int nrows, int ntiles) {
    __shared__ __align__(16) float Wl[TD * TD];     // 64 KB
    __shared__ __align__(16) float Xl[128 * 132];   // 67.6 KB (pad 132: b128 X reads conflict-free)
    const int t = threadIdx.x;
    {
        const float4* W4 = (const float4*)W;
        float4* Wl4 = (float4*)Wl;
#pragma unroll
        for (int i = 0; i < 16; ++i) Wl4[t + i * 256] = W4[t + i * 256];
    }
    const int tx = t & 15, ty = t >> 4;   // ty in 0..15
    const int c0 = tx * 4;

    for (int tile = blockIdx.x; tile < ntiles; tile += gridDim.x) {
        const int rbase = tile * 128;
        __syncthreads();   // protect Xl (prev iter readers; also orders first Wl stage)
        for (int i = t; i < 128 * 32; i += 256) {
            int row = i >> 5, c4 = i & 31;
            int gr = rbase + row;
            float4 v = make_float4(0.f, 0.f, 0.f, 0.f);
            if (gr < nrows) v = ((const float4*)(X + (size_t)gr * TD))[c4];
            ((float4*)(Xl + row * 132))[c4] = v;
        }
        __syncthreads();

        float acc[8][8];
#pragma unroll
        for (int j = 0; j < 8; ++j)
#pragma unroll
            for (int c = 0; c < 8; ++c) acc[j][c] = 0.f;

        for (int k0 = 0; k0 < TD; k0 += 4) {
            float4 xr[8];
#pragma unroll
            for (int j = 0; j < 8; ++j)
                xr[j] = *(const float4*)&Xl[(ty + 16 * j) * 132 + k0];
#pragma unroll
            for (int kk = 0; kk < 4; ++kk) {
                float4 w0 = *(const float4*)&Wl[(k0 + kk) * TD + c0];
                float4 w1 = *(const float4*)&Wl[(k0 + kk) * TD + 64 + c0];
#pragma unroll
                for (int j = 0; j < 8; ++j) {
                    float x = (kk == 0) ? xr[j].x : (kk == 1) ? xr[j].y : (kk == 2) ? xr[j].z : xr[j].w;
                    acc[j][0] = fmaf(x, w0.x, acc[j][0]);
                    acc[j][1] = fmaf(x, w0.y, acc[j][1]);
                    acc[j][2] = fmaf(x, w0.z, acc[j][2]);
                    acc[j][3] = fmaf(x, w0.w, acc[j][3]);
                    acc[j][4] = fmaf(x, w1.x, acc[j][4]);
                    acc[j][5] = fmaf(x, w1.y, acc[j][5]);
                    acc[j][6] = fmaf(x, w1.z, acc[j][6]);
                    acc[j][7] = fmaf(x, w1.w, acc[j][7]);
                }
            }
        }

#pragma unroll
        for (int j = 0; j < 8; ++j) {
            int gr = rbase + ty + 16 * j;
            if (gr < nrows) {
                float s = scale[gr];
                unsigned short* o = out + (size_t)gr * TD;
                ushort4 p0, p1;
                p0.x = f2bf(acc[j][0] * s); p0.y = f2bf(acc[j][1] * s);
                p0.z = f2bf(acc[j][2] * s); p0.w = f2bf(acc[j][3] * s);
                p1.x = f2bf(acc[j][4] * s); p1.y = f2bf(acc[j][5] * s);
                p1.z = f2bf(acc[j][6] * s); p1.w = f2bf(acc[j][7] * s);
                *(ushort4*)(o + c0) = p0;
                *(ushort4*)(o + 64 + c0) = p1;
            }
        }
    }
}

// ---------------- CSR aggregation: bf16 gather, f64 accumulate (order-invariant), f32 out ----------------
// one node per 16 lanes; lane reads 8 bf16 (16 B) per edge -> 256 B per edge gather.
__global__ __launch_bounds__(256) void k_agg(const unsigned short* __restrict__ hs, const int* __restrict__ rowptr,
                                             const int* __restrict__ esrc, const float* __restrict__ dinv,
                                             const float* __restrict__ bias, float* __restrict__ out,
                                             int n, int relu) {
    int node = blockIdx.x * 16 + (threadIdx.x >> 4);
    int lane = threadIdx.x & 15;
    if (node >= n) return;
    int s = rowptr[node], e = rowptr[node + 1];
    const uint4* h16 = (const uint4*)hs;
    double a0 = 0, a1 = 0, a2 = 0, a3 = 0, a4 = 0, a5 = 0, a6 = 0, a7 = 0;
    int i = s;
    for (; i + 2 <= e; i += 2) {
        uint4 u = h16[(size_t)esrc[i] * 16 + lane];
        uint4 v = h16[(size_t)esrc[i + 1] * 16 + lane];
        a0 += (double)__uint_as_float(u.x << 16); a1 += (double)__uint_as_float(u.x & 0xffff0000u);
        a2 += (double)__uint_as_float(u.y << 16); a3 += (double)__uint_as_float(u.y & 0xffff0000u);
        a4 += (double)__uint_as_float(u.z << 16); a5 += (double)__uint_as_float(u.z & 0xffff0000u);
        a6 += (double)__uint_as_float(u.w << 16); a7 += (double)__uint_as_float(u.w & 0xffff0000u);
        a0 += (double)__uint_as_float(v.x << 16); a1 += (double)__uint_as_float(v.x & 0xffff0000u);
        a2 += (double)__uint_as_float(v.y << 16); a3 += (double)__uint_as_float(v.y & 0xffff0000u);
        a4 += (double)__uint_as_float(v.z << 16); a5 += (double)__uint_as_float(v.z & 0xffff0000u);
        a6 += (double)__uint_as_float(v.w << 16); a7 += (double)__uint_as_float(v.w & 0xffff0000u);
    }
    if (i < e) {
        uint4 u = h16[(size_t)esrc[i] * 16 + lane];
        a0 += (double)__uint_as_float(u.x << 16); a1 += (double)__uint_as_float(u.x & 0xffff0000u);
        a2 += (double)__uint_as_float(u.y << 16); a3 += (double)__uint_as_float(u.y & 0xffff0000u);
        a4 += (double)__uint_as_float(u.z << 16); a5 += (double)__uint_as_float(u.z & 0xffff0000u);
        a6 += (double)__uint_as_float(u.w << 16); a7 += (double)__uint_as_float(u.w & 0xffff0000u);
    }
    double di = (double)dinv[node];
    float4 b0 = ((const float4*)bias)[lane * 2];
    float4 b1 = ((const float4*)bias)[lane * 2 + 1];
    float o0 = (float)(di * a0 + (double)b0.x);
    float o1 = (float)(di * a1 + (double)b0.y);
    float o2 = (float)(di * a2 + (double)b0.z);
    float o3 = (float)(di * a3 + (double)b0.w);
    float o4 = (float)(di * a4 + (double)b1.x);
    float o5 = (float)(di * a5 + (double)b1.y);
    float o6 = (float)(di * a6 + (double)b1.z);
    float o7 = (float)(di * a7 + (double)b1.w);
    if (relu) {
        o0 = fmaxf(o0, 0.f); o1 = fmaxf(o1, 0.f); o2 = fmaxf(o2, 0.f); o3 = fmaxf(o3, 0.f);
        o4 = fmaxf(o4, 0.f); o5 = fmaxf(o5, 0.f); o6 = fmaxf(o6, 0.f); o7 = fmaxf(o7, 0.f);
    }
    float4 r0 = make_float4(o0, o1, o2, o3);
    float4 r1 = make_float4(o4, o5, o6, o7);
    ((float4*)out)[(size_t)node * 32 + lane * 2]     = r0;
    ((float4*)out)[(size_t)node * 32 + lane * 2 + 1] = r1;
}

// ---------------- scoring: out[e] = z[head]^T W[rel] z[tail] ----------------
__global__ __launch_bounds__(128) void k_score(const float* __restrict__ z, const float* __restrict__ relW,
                                               const int* __restrict__ rel, const int* __restrict__ head,
                                               const int* __restrict__ tail, float* __restrict__ out, int es) {
    int e = blockIdx.x;
    int j = threadIdx.x;
    __shared__ float zh[TD];
    __shared__ float red[2];
    int r = rel[e], h = head[e], tl = tail[e];
    zh[j] = z[(size_t)h * TD + j];
    float ztj = z[(size_t)tl * TD + j];
    __syncthreads();
    const float* W = relW + (size_t)r * TD * TD;
    float acc = 0.f;
#pragma unroll 8
    for (int i = 0; i < TD; ++i) acc = fmaf(zh[i], W[i * TD + j], acc);
    acc *= ztj;
#pragma unroll
    for (int off = 32; off > 0; off >>= 1) acc += __shfl_down(acc, off);
    if ((j & 63) == 0) red[j >> 6] = acc;
    __syncthreads();
    if (j == 0) out[e] = red[0] + red[1];
}

extern "C" void kernel_launch(void* const* d_in, const int* in_sizes, int n_in,
                              void* d_out, int out_size, void* d_ws, size_t ws_size,
                              hipStream_t stream) {
    const float* x0   = (const float*)d_in[0];
    const float* W1   = (const float*)d_in[1];
    const float* b1   = (const float*)d_in[2];
    const float* W2   = (const float*)d_in[3];
    const float* b2   = (const float*)d_in[4];
    const float* relW = (const float*)d_in[5];
    const int*   ei   = (const int*)d_in[6];
    const int*   rel  = (const int*)d_in[7];
    const int*   head = (const int*)d_in[8];
    const int*   tail = (const int*)d_in[9];
    float* outp = (float*)d_out;

    const int N_  = in_sizes[0] / TD;
    const int E_  = in_sizes[6] / 2;
    const int ES_ = in_sizes[7];
    const int nb  = (N_ + 1023) / 1024;
    const int ntiles = (N_ + 127) / 128;

    char* p = (char*)d_ws;
    auto alloc = [&](size_t bytes) { char* r = p; p += (bytes + 255) & ~(size_t)255; return r; };
    int*            deg    = (int*)           alloc((size_t)N_ * 4);
    float*          dinv   = (float*)         alloc((size_t)N_ * 4);
    int*            rowptr = (int*)           alloc(((size_t)N_ + 1) * 4);
    int*            bsums  = (int*)           alloc((size_t)nb * 4);
    int*            esrc   = (int*)           alloc((size_t)E_ * 4);
    unsigned short* bufA   = (unsigned short*)alloc((size_t)N_ * TD * 2);   // bf16 h-scaled
    float*          bufB   = (float*)         alloc((size_t)N_ * TD * 4);   // f32 conv out
    int*            rank   = (int*)bufA;   // alias: dead before first k_gemm writes bufA (E*4 <= N*TD*2)

    hipMemsetAsync(deg, 0, (size_t)N_ * 4, stream);
    k_rank  <<<(E_ + 255) / 256, 256, 0, stream>>>(ei, deg, rank, E_);
    k_dinv  <<<(N_ + 255) / 256, 256, 0, stream>>>(deg, dinv, N_);
    k_scan1 <<<nb, 256, 0, stream>>>(deg, rowptr, bsums, N_);
    k_scan2 <<<1, 256, 0, stream>>>(bsums, nb, rowptr + N_);
    k_scan3 <<<(N_ + 255) / 256, 256, 0, stream>>>(rowptr, bsums, N_);
    k_place <<<(E_ + 255) / 256, 256, 0, stream>>>(ei, rowptr, rank, esrc, E_);

    // conv1: bufA = bf16(dinv * (x0 @ W1)); bufB = relu(dinv*agg(bufA) + b1)
    k_gemm<<<256, 256, 0, stream>>>(x0, W1, dinv, bufA, N_, ntiles);
    k_agg <<<(N_ + 15) / 16, 256, 0, stream>>>(bufA, rowptr, esrc, dinv, b1, bufB, N_, 1);
    // conv2: bufA = bf16(dinv * (bufB @ W2)); bufB = dinv*agg(bufA) + b2  (= z)
    k_gemm<<<256, 256, 0, stream>>>(bufB, W2, dinv, bufA, N_, ntiles);
    k_agg <<<(N_ + 15) / 16, 256, 0, stream>>>(bufA, rowptr, esrc, dinv, b2, bufB, N_, 0);

    k_score<<<ES_, 128, 0, stream>>>(bufB, relW, rel, head, tail, outp, ES_);
}

// Round 5
// 501.051 us; speedup vs baseline: 1.5759x; 1.1236x over previous
//
#include <hip/hip_runtime.h>
#include <hip/hip_bf16.h>

#define TD 128   // feature dim, fixed by problem
#define XS 136   // padded X-tile row stride in bf16 (+8 keeps b128 align, breaks bank conflicts)

typedef __attribute__((ext_vector_type(8))) short bf16x8;   // 8 bf16 = 4 VGPR (MFMA A/B frag)
typedef __attribute__((ext_vector_type(4))) float f32x4;    // MFMA C/D frag

static __device__ __forceinline__ unsigned short f2bf(float f) {
    unsigned int u = __float_as_uint(f);
    u += 0x7fffu + ((u >> 16) & 1u);   // round-to-nearest-even
    return (unsigned short)(u >> 16);
}
static __device__ __forceinline__ float bf2f(unsigned short h) {
    return __uint_as_float((unsigned int)h << 16);
}

// ---------------- pass 1: degree + within-bucket rank (single atomic pass) ----------------
__global__ __launch_bounds__(256) void k_rank(const int* __restrict__ ei, int* __restrict__ deg,
                                              int* __restrict__ rank, int E_) {
    int e = blockIdx.x * 256 + threadIdx.x;
    if (e < E_) rank[e] = atomicAdd(&deg[ei[E_ + e]], 1);   // dst = row 1
}

__global__ __launch_bounds__(256) void k_dinv(const int* __restrict__ deg, float* __restrict__ dinv, int n) {
    int i = blockIdx.x * 256 + threadIdx.x;
    if (i < n) {
        int d = deg[i];
        dinv[i] = (d > 0) ? 1.0f / sqrtf((float)d) : 0.0f;
    }
}

// ---------------- exclusive scan (3-kernel hierarchical) ----------------
__global__ __launch_bounds__(256) void k_scan1(const int* __restrict__ deg, int* __restrict__ rowptr,
                                               int* __restrict__ bsums, int n) {
    __shared__ int wsum[4];
    int t = threadIdx.x;
    int base = blockIdx.x * 1024 + t * 4;
    int a0 = 0, a1 = 0, a2 = 0, a3 = 0;
    if (base + 3 < n) {
        int4 v = *(const int4*)(deg + base);
        a0 = v.x; a1 = v.y; a2 = v.z; a3 = v.w;
    } else {
        if (base     < n) a0 = deg[base];
        if (base + 1 < n) a1 = deg[base + 1];
        if (base + 2 < n) a2 = deg[base + 2];
        if (base + 3 < n) a3 = deg[base + 3];
    }
    int s1 = a0 + a1, s2 = s1 + a2, tot = s2 + a3;
    int lane = t & 63, wv = t >> 6;
    int x = tot;
#pragma unroll
    for (int off = 1; off < 64; off <<= 1) {
        int y = __shfl_up(x, off);
        if (lane >= off) x += y;
    }
    if (lane == 63) wsum[wv] = x;
    __syncthreads();
    int woff = 0;
    for (int w = 0; w < wv; ++w) woff += wsum[w];
    int excl = woff + x - tot;
    if (base     < n) rowptr[base]     = excl;
    if (base + 1 < n) rowptr[base + 1] = excl + a0;
    if (base + 2 < n) rowptr[base + 2] = excl + s1;
    if (base + 3 < n) rowptr[base + 3] = excl + s2;
    if (t == 255) bsums[blockIdx.x] = woff + x;   // block total
}

// parallel single-block scan of block sums (nb <= 1024)
__global__ __launch_bounds__(256) void k_scan2(int* __restrict__ bsums, int nb, int* __restrict__ rowptrN) {
    __shared__ int wsum[4];
    int t = threadIdx.x;
    int base = t * 4;
    int a0 = (base     < nb) ? bsums[base]     : 0;
    int a1 = (base + 1 < nb) ? bsums[base + 1] : 0;
    int a2 = (base + 2 < nb) ? bsums[base + 2] : 0;
    int a3 = (base + 3 < nb) ? bsums[base + 3] : 0;
    int s1 = a0 + a1, s2 = s1 + a2, tot = s2 + a3;
    int lane = t & 63, wv = t >> 6;
    int x = tot;
#pragma unroll
    for (int off = 1; off < 64; off <<= 1) {
        int y = __shfl_up(x, off);
        if (lane >= off) x += y;
    }
    if (lane == 63) wsum[wv] = x;
    __syncthreads();
    int woff = 0;
    for (int w = 0; w < wv; ++w) woff += wsum[w];
    int excl = woff + x - tot;
    if (base     < nb) bsums[base]     = excl;
    if (base + 1 < nb) bsums[base + 1] = excl + a0;
    if (base + 2 < nb) bsums[base + 2] = excl + s1;
    if (base + 3 < nb) bsums[base + 3] = excl + s2;
    if (t == 255) *rowptrN = woff + x;   // grand total = E
}

__global__ __launch_bounds__(256) void k_scan3(int* __restrict__ rowptr, const int* __restrict__ bsums, int n) {
    int i = blockIdx.x * 256 + threadIdx.x;
    if (i < n) rowptr[i] += bsums[i >> 10];
}

// ---------------- pass 2: atomic-free placement ----------------
__global__ __launch_bounds__(256) void k_place(const int* __restrict__ ei, const int* __restrict__ rowptr,
                                               const int* __restrict__ rank, int* __restrict__ esrc, int E_) {
    int e = blockIdx.x * 256 + threadIdx.x;
    if (e < E_) {
        int s = ei[e];
        int d = ei[E_ + e];
        esrc[rowptr[d] + rank[e]] = s;
    }
}

// ---------------- W transpose + hi/lo bf16 split ----------------
// Wt layout: 4 planes of 128x128 bf16, n-major: plane[p][n*128+k]
//   p0=W1 hi, p1=W1 lo, p2=W2 hi, p3=W2 lo;  Wt[n][k] corresponds to W[k][n].
__global__ __launch_bounds__(256) void k_wsplit(const float* __restrict__ W1, const float* __restrict__ W2,
                                                unsigned short* __restrict__ Wt) {
    int i = blockIdx.x * 256 + threadIdx.x;   // 0 .. 2*16384-1
    int w = i >> 14;
    int idx = i & 16383;          // = k*128 + n  (coalesced read)
    int k = idx >> 7, n = idx & 127;
    float x = (w ? W2 : W1)[idx];
    unsigned short h = f2bf(x);
    unsigned short l = f2bf(x - bf2f(h));
    size_t base = (size_t)w * 32768;
    Wt[base + n * 128 + k] = h;
    Wt[base + 16384 + n * 128 + k] = l;
}

// ---------------- MFMA GEMM: out[r][c] = bf16(scale[r] * sum_k X[r][k]*W[k][c]) ----------------
// f32-equivalent precision via bf16 hi/lo split: A*B ~= Ah*Bh + Al*Bh + Ah*Bl  (rel err ~2^-18).
// 256 thr = 4 waves; 128-row tiles; wave w owns rows [w*32, w*32+32) x all 128 cols
// = 2x8 grid of 16x16x32 MFMA tiles. X staged in LDS (hi+lo, 68 KB -> 2 blocks/CU);
// W frags read directly from pre-transposed global Wt (L1/L2-resident, 64 KB/plane).
__global__ __launch_bounds__(256) void k_gemm(const float* __restrict__ X,
                                              const unsigned short* __restrict__ Wth,
                                              const unsigned short* __restrict__ Wtl,
                                              const float* __restrict__ scale,
                                              unsigned short* __restrict__ out,
                                              int nrows, int ntiles) {
    __shared__ __align__(16) unsigned short Xh[128 * XS];   // 34 KB (reused as C-stage in epilogue)
    __shared__ __align__(16) unsigned short Xl[128 * XS];   // 34 KB
    const int t = threadIdx.x;
    const int w = t >> 6;
    const int lane = t & 63;
    const int l15 = lane & 15;
    const int quad = lane >> 4;
    const int m0 = w * 32;

    for (int tile = blockIdx.x; tile < ntiles; tile += gridDim.x) {
        const int rbase = tile * 128;
        __syncthreads();   // prev-tile copy-out readers done before X restage
#pragma unroll
        for (int it = 0; it < 16; ++it) {
            int idx = t + it * 256;              // 4096 float4 groups
            int row = idx >> 5, c4 = idx & 31;
            int gr = rbase + row;
            float4 v = make_float4(0.f, 0.f, 0.f, 0.f);
            if (gr < nrows) v = ((const float4*)(X + (size_t)gr * TD))[c4];
            unsigned short h0 = f2bf(v.x), h1 = f2bf(v.y), h2 = f2bf(v.z), h3 = f2bf(v.w);
            ushort4 hh, ll;
            hh.x = h0; hh.y = h1; hh.z = h2; hh.w = h3;
            ll.x = f2bf(v.x - bf2f(h0)); ll.y = f2bf(v.y - bf2f(h1));
            ll.z = f2bf(v.z - bf2f(h2)); ll.w = f2bf(v.w - bf2f(h3));
            *(ushort4*)&Xh[row * XS + c4 * 4] = hh;
            *(ushort4*)&Xl[row * XS + c4 * 4] = ll;
        }
        __syncthreads();

        f32x4 acc[2][8];
#pragma unroll
        for (int a = 0; a < 2; ++a)
#pragma unroll
            for (int b = 0; b < 8; ++b) acc[a][b] = (f32x4){0.f, 0.f, 0.f, 0.f};

#pragma unroll
        for (int kc = 0; kc < 4; ++kc) {
            const int koff = kc * 32 + quad * 8;
            bf16x8 ah0 = *(const bf16x8*)&Xh[(m0 + l15) * XS + koff];
            bf16x8 ah1 = *(const bf16x8*)&Xh[(m0 + 16 + l15) * XS + koff];
            bf16x8 al0 = *(const bf16x8*)&Xl[(m0 + l15) * XS + koff];
            bf16x8 al1 = *(const bf16x8*)&Xl[(m0 + 16 + l15) * XS + koff];
#pragma unroll
            for (int b = 0; b < 8; ++b) {
                const size_t boff = (size_t)(b * 16 + l15) * 128 + koff;
                bf16x8 bh = *(const bf16x8*)&Wth[boff];
                bf16x8 bl = *(const bf16x8*)&Wtl[boff];
                acc[0][b] = __builtin_amdgcn_mfma_f32_16x16x32_bf16(ah0, bh, acc[0][b], 0, 0, 0);
                acc[1][b] = __builtin_amdgcn_mfma_f32_16x16x32_bf16(ah1, bh, acc[1][b], 0, 0, 0);
                acc[0][b] = __builtin_amdgcn_mfma_f32_16x16x32_bf16(al0, bh, acc[0][b], 0, 0, 0);
                acc[1][b] = __builtin_amdgcn_mfma_f32_16x16x32_bf16(al1, bh, acc[1][b], 0, 0, 0);
                acc[0][b] = __builtin_amdgcn_mfma_f32_16x16x32_bf16(ah0, bl, acc[0][b], 0, 0, 0);
                acc[1][b] = __builtin_amdgcn_mfma_f32_16x16x32_bf16(ah1, bl, acc[1][b], 0, 0, 0);
            }
        }
        __syncthreads();   // all X reads done; Xh becomes C-stage

        // epilogue: C/D layout col=lane&15, row=quad*4+reg -> scale, bf16, stage to LDS
#pragma unroll
        for (int a = 0; a < 2; ++a) {
            int lrow = m0 + a * 16 + quad * 4;       // local row of reg 0 (multiple of 4)
            int grow = rbase + lrow;
            float4 s4 = make_float4(0.f, 0.f, 0.f, 0.f);
            if (grow < nrows) s4 = *(const float4*)&scale[grow];   // nrows % 4 == 0
#pragma unroll
            for (int b = 0; b < 8; ++b) {
                int col = b * 16 + l15;
                Xh[(lrow + 0) * XS + col] = f2bf(acc[a][b][0] * s4.x);
                Xh[(lrow + 1) * XS + col] = f2bf(acc[a][b][1] * s4.y);
                Xh[(lrow + 2) * XS + col] = f2bf(acc[a][b][2] * s4.z);
                Xh[(lrow + 3) * XS + col] = f2bf(acc[a][b][3] * s4.w);
            }
        }
        __syncthreads();

        // coalesced copy-out: 8 rounds x (16 rows x 256 B)
#pragma unroll
        for (int rr = 0; rr < 8; ++rr) {
            int row = rr * 16 + (t >> 4);
            int gr = rbase + row;
            if (gr < nrows) {
                uint4 v = *(const uint4*)&Xh[row * XS + (t & 15) * 8];
                *(uint4*)(out + (size_t)gr * TD + (t & 15) * 8) = v;
            }
        }
    }
}

// ---------------- CSR aggregation: bf16 gather, f64 accumulate (order-invariant), f32 out ----------------
__global__ __launch_bounds__(256) void k_agg(const unsigned short* __restrict__ hs, const int* __restrict__ rowptr,
                                             const int* __restrict__ esrc, const float* __restrict__ dinv,
                                             const float* __restrict__ bias, float* __restrict__ out,
                                             int n, int relu) {
    int node = blockIdx.x * 16 + (threadIdx.x >> 4);
    int lane = threadIdx.x & 15;
    if (node >= n) return;
    int s = rowptr[node], e = rowptr[node + 1];
    const uint4* h16 = (const uint4*)hs;
    double a0 = 0, a1 = 0, a2 = 0, a3 = 0, a4 = 0, a5 = 0, a6 = 0, a7 = 0;
    int i = s;
    for (; i + 2 <= e; i += 2) {
        uint4 u = h16[(size_t)esrc[i] * 16 + lane];
        uint4 v = h16[(size_t)esrc[i + 1] * 16 + lane];
        a0 += (double)__uint_as_float(u.x << 16); a1 += (double)__uint_as_float(u.x & 0xffff0000u);
        a2 += (double)__uint_as_float(u.y << 16); a3 += (double)__uint_as_float(u.y & 0xffff0000u);
        a4 += (double)__uint_as_float(u.z << 16); a5 += (double)__uint_as_float(u.z & 0xffff0000u);
        a6 += (double)__uint_as_float(u.w << 16); a7 += (double)__uint_as_float(u.w & 0xffff0000u);
        a0 += (double)__uint_as_float(v.x << 16); a1 += (double)__uint_as_float(v.x & 0xffff0000u);
        a2 += (double)__uint_as_float(v.y << 16); a3 += (double)__uint_as_float(v.y & 0xffff0000u);
        a4 += (double)__uint_as_float(v.z << 16); a5 += (double)__uint_as_float(v.z & 0xffff0000u);
        a6 += (double)__uint_as_float(v.w << 16); a7 += (double)__uint_as_float(v.w & 0xffff0000u);
    }
    if (i < e) {
        uint4 u = h16[(size_t)esrc[i] * 16 + lane];
        a0 += (double)__uint_as_float(u.x << 16); a1 += (double)__uint_as_float(u.x & 0xffff0000u);
        a2 += (double)__uint_as_float(u.y << 16); a3 += (double)__uint_as_float(u.y & 0xffff0000u);
        a4 += (double)__uint_as_float(u.z << 16); a5 += (double)__uint_as_float(u.z & 0xffff0000u);
        a6 += (double)__uint_as_float(u.w << 16); a7 += (double)__uint_as_float(u.w & 0xffff0000u);
    }
    double di = (double)dinv[node];
    float4 b0 = ((const float4*)bias)[lane * 2];
    float4 b1 = ((const float4*)bias)[lane * 2 + 1];
    float o0 = (float)(di * a0 + (double)b0.x);
    float o1 = (float)(di * a1 + (double)b0.y);
    float o2 = (float)(di * a2 + (double)b0.z);
    float o3 = (float)(di * a3 + (double)b0.w);
    float o4 = (float)(di * a4 + (double)b1.x);
    float o5 = (float)(di * a5 + (double)b1.y);
    float o6 = (float)(di * a6 + (double)b1.z);
    float o7 = (float)(di * a7 + (double)b1.w);
    if (relu) {
        o0 = fmaxf(o0, 0.f); o1 = fmaxf(o1, 0.f); o2 = fmaxf(o2, 0.f); o3 = fmaxf(o3, 0.f);
        o4 = fmaxf(o4, 0.f); o5 = fmaxf(o5, 0.f); o6 = fmaxf(o6, 0.f); o7 = fmaxf(o7, 0.f);
    }
    ((float4*)out)[(size_t)node * 32 + lane * 2]     = make_float4(o0, o1, o2, o3);
    ((float4*)out)[(size_t)node * 32 + lane * 2 + 1] = make_float4(o4, o5, o6, o7);
}

// ---------------- scoring: out[e] = z[head]^T W[rel] z[tail] ----------------
__global__ __launch_bounds__(128) void k_score(const float* __restrict__ z, const float* __restrict__ relW,
                                               const int* __restrict__ rel, const int* __restrict__ head,
                                               const int* __restrict__ tail, float* __restrict__ out, int es) {
    int e = blockIdx.x;
    int j = threadIdx.x;
    __shared__ float zh[TD];
    __shared__ float red[2];
    int r = rel[e], h = head[e], tl = tail[e];
    zh[j] = z[(size_t)h * TD + j];
    float ztj = z[(size_t)tl * TD + j];
    __syncthreads();
    const float* W = relW + (size_t)r * TD * TD;
    float acc = 0.f;
#pragma unroll 8
    for (int i = 0; i < TD; ++i) acc = fmaf(zh[i], W[i * TD + j], acc);
    acc *= ztj;
#pragma unroll
    for (int off = 32; off > 0; off >>= 1) acc += __shfl_down(acc, off);
    if ((j & 63) == 0) red[j >> 6] = acc;
    __syncthreads();
    if (j == 0) out[e] = red[0] + red[1];
}

extern "C" void kernel_launch(void* const* d_in, const int* in_sizes, int n_in,
                              void* d_out, int out_size, void* d_ws, size_t ws_size,
                              hipStream_t stream) {
    const float* x0   = (const float*)d_in[0];
    const float* W1   = (const float*)d_in[1];
    const float* b1   = (const float*)d_in[2];
    const float* W2   = (const float*)d_in[3];
    const float* b2   = (const float*)d_in[4];
    const float* relW = (const float*)d_in[5];
    const int*   ei   = (const int*)d_in[6];
    const int*   rel  = (const int*)d_in[7];
    const int*   head = (const int*)d_in[8];
    const int*   tail = (const int*)d_in[9];
    float* outp = (float*)d_out;

    const int N_  = in_sizes[0] / TD;
    const int E_  = in_sizes[6] / 2;
    const int ES_ = in_sizes[7];
    const int nb  = (N_ + 1023) / 1024;
    const int ntiles = (N_ + 127) / 128;

    char* p = (char*)d_ws;
    auto alloc = [&](size_t bytes) { char* r = p; p += (bytes + 255) & ~(size_t)255; return r; };
    int*            deg    = (int*)           alloc((size_t)N_ * 4);
    float*          dinv   = (float*)         alloc((size_t)N_ * 4);
    int*            rowptr = (int*)           alloc(((size_t)N_ + 1) * 4);
    int*            bsums  = (int*)           alloc((size_t)nb * 4);
    int*            esrc   = (int*)           alloc((size_t)E_ * 4);
    unsigned short* Wt     = (unsigned short*)alloc((size_t)4 * 16384 * 2);   // W1h,W1l,W2h,W2l
    unsigned short* bufA   = (unsigned short*)alloc((size_t)N_ * TD * 2);     // bf16 h-scaled
    float*          bufB   = (float*)         alloc((size_t)N_ * TD * 4);     // f32 conv out
    int*            rank   = (int*)bufA;   // alias: dead before first k_gemm writes bufA (E*4 <= N*TD*2)

    hipMemsetAsync(deg, 0, (size_t)N_ * 4, stream);
    k_rank  <<<(E_ + 255) / 256, 256, 0, stream>>>(ei, deg, rank, E_);
    k_dinv  <<<(N_ + 255) / 256, 256, 0, stream>>>(deg, dinv, N_);
    k_scan1 <<<nb, 256, 0, stream>>>(deg, rowptr, bsums, N_);
    k_scan2 <<<1, 256, 0, stream>>>(bsums, nb, rowptr + N_);
    k_scan3 <<<(N_ + 255) / 256, 256, 0, stream>>>(rowptr, bsums, N_);
    k_place <<<(E_ + 255) / 256, 256, 0, stream>>>(ei, rowptr, rank, esrc, E_);
    k_wsplit<<<128, 256, 0, stream>>>(W1, W2, Wt);

    // conv1: bufA = bf16(dinv * (x0 @ W1)); bufB = relu(dinv*agg(bufA) + b1)
    k_gemm<<<512, 256, 0, stream>>>(x0, Wt, Wt + 16384, dinv, bufA, N_, ntiles);
    k_agg <<<(N_ + 15) / 16, 256, 0, stream>>>(bufA, rowptr, esrc, dinv, b1, bufB, N_, 1);
    // conv2: bufA = bf16(dinv * (bufB @ W2)); bufB = dinv*agg(bufA) + b2  (= z)
    k_gemm<<<512, 256, 0, stream>>>(bufB, Wt + 32768, Wt + 49152, dinv, bufA, N_, ntiles);
    k_agg <<<(N_ + 15) / 16, 256, 0, stream>>>(bufA, rowptr, esrc, dinv, b2, bufB, N_, 0);

    k_score<<<ES_, 128, 0, stream>>>(bufB, relW, rel, head, tail, outp, ES_);
}